// Round 4
// baseline (820.158 us; speedup 1.0000x reference)
//
#include <hip/hip_runtime.h>
#include <hip/hip_bf16.h>

#define NN 50000
#define EE 1600000
#define NEDGE (EE + NN)   // with self loops
#define HH 4
#define HC 128
#define GG 64
#define GMT 64            // nodes per gemm block
#define NXCD 8
#define RNG (NN / NXCD)   // 6250 nodes per XCD group
#define HB 8              // hist sub-blocks per group
#define SB 32             // scatter sub-blocks per group

__device__ __forceinline__ float lrelu(float x) { return x > 0.f ? x : 0.2f * x; }

// ---------------- CSR build (XCD-range-partitioned) ----------------
// group g = blockIdx&7 owns dst range [g*RNG, (g+1)*RNG). Real edges only;
// self-loops are accounted analytically (deg+1 in scan, appended in scatter).
__global__ __launch_bounds__(256) void hist2(const int* __restrict__ ei, int* __restrict__ deg) {
    __shared__ int lh[RNG];
    int g = blockIdx.x & (NXCD - 1);
    int sub = blockIdx.x >> 3;
    int t = threadIdx.x;
    for (int i = t; i < RNG; i += 256) lh[i] = 0;
    __syncthreads();
    int lo = g * RNG;
    const int per = (EE + HB - 1) / HB;
    int e0 = sub * per, e1 = e0 + per; if (e1 > EE) e1 = EE;
    for (int i = e0 + t; i < e1; i += 256) {
        int d = ei[EE + i];
        unsigned r = (unsigned)(d - lo);
        if (r < RNG) atomicAdd(&lh[r], 1);
    }
    __syncthreads();
    for (int i = t; i < RNG; i += 256) {
        int v = lh[i];
        if (v) atomicAdd(&deg[lo + i], v);
    }
}

// one block; deg[i]+1 accounts for the self loop; writes row_start AND cursor
__global__ __launch_bounds__(1024) void scan_deg(const int* __restrict__ deg,
                                                 int* __restrict__ row_start,
                                                 int* __restrict__ cursor) {
    __shared__ int sums[1024];
    int t = threadIdx.x;
    const int per = (NN + 1023) / 1024;
    int lo = t * per, hi = lo + per; if (hi > NN) hi = NN;
    int s = 0;
    for (int i = lo; i < hi; ++i) s += deg[i] + 1;
    sums[t] = s;
    __syncthreads();
    for (int off = 1; off < 1024; off <<= 1) {
        int v = (t >= off) ? sums[t - off] : 0;
        __syncthreads();
        sums[t] += v;
        __syncthreads();
    }
    int run = sums[t] - s;
    for (int i = lo; i < hi; ++i) {
        row_start[i] = run;
        cursor[i] = run;
        run += deg[i] + 1;
    }
    if (t == 0) row_start[NN] = NEDGE;
}

__global__ __launch_bounds__(256) void scatter2(const int* __restrict__ ei, int* __restrict__ cursor,
                                                int* __restrict__ esrc) {
    int g = blockIdx.x & (NXCD - 1);
    int sub = blockIdx.x >> 3;
    int t = threadIdx.x;
    int lo = g * RNG;
    const int per = (EE + SB - 1) / SB;
    int e0 = sub * per, e1 = e0 + per; if (e1 > EE) e1 = EE;
    for (int i = e0 + t; i < e1; i += 256) {
        int d = ei[EE + i];
        unsigned r = (unsigned)(d - lo);
        if (r < RNG) {
            int s = ei[i];
            int pos = atomicAdd(&cursor[d], 1);
            esrc[pos] = s;
        }
    }
    // self loops for this group's node slice
    const int perN = (RNG + SB - 1) / SB;
    int n0 = lo + sub * perN, n1 = n0 + perN; if (n1 > lo + RNG) n1 = lo + RNG;
    for (int n = n0 + t; n < n1; n += 256) {
        int pos = atomicAdd(&cursor[n], 1);
        esrc[pos] = n;
    }
}

// ---------------- GEMM (X @ W) + per-head alpha dots ----------------
__global__ __launch_bounds__(256) void gemm_alpha(
    const float* __restrict__ X, const float* __restrict__ W,
    const float* __restrict__ a_src, const float* __restrict__ a_dst,
    float* __restrict__ xw, float* __restrict__ as_, float* __restrict__ ad_) {
    __shared__ float xs[GMT][HC + 4];
    int tid = threadIdx.x;
    int n0 = blockIdx.x * GMT;
    for (int i = tid; i < GMT * (HC / 4); i += 256) {
        int r = i >> 5, c4 = i & 31;
        int n = n0 + r;
        float4 v = (n < NN) ? ((const float4*)X)[(size_t)n * 32 + c4]
                            : make_float4(0.f, 0.f, 0.f, 0.f);
        *(float4*)&xs[r][c4 * 4] = v;
    }
    __syncthreads();

    int jg = tid & 31;
    int ng = tid >> 5;
    float4 acc[8] = {};
    for (int k = 0; k < HC; k += 4) {
        float4 wr[4];
#pragma unroll
        for (int dk = 0; dk < 4; ++dk) wr[dk] = ((const float4*)W)[(k + dk) * 32 + jg];
#pragma unroll
        for (int r = 0; r < 8; ++r) {
            float4 xv = *(const float4*)&xs[ng * 8 + r][k];
            acc[r].x = fmaf(xv.x, wr[0].x, acc[r].x);
            acc[r].y = fmaf(xv.x, wr[0].y, acc[r].y);
            acc[r].z = fmaf(xv.x, wr[0].z, acc[r].z);
            acc[r].w = fmaf(xv.x, wr[0].w, acc[r].w);
            acc[r].x = fmaf(xv.y, wr[1].x, acc[r].x);
            acc[r].y = fmaf(xv.y, wr[1].y, acc[r].y);
            acc[r].z = fmaf(xv.y, wr[1].z, acc[r].z);
            acc[r].w = fmaf(xv.y, wr[1].w, acc[r].w);
            acc[r].x = fmaf(xv.z, wr[2].x, acc[r].x);
            acc[r].y = fmaf(xv.z, wr[2].y, acc[r].y);
            acc[r].z = fmaf(xv.z, wr[2].z, acc[r].z);
            acc[r].w = fmaf(xv.z, wr[2].w, acc[r].w);
            acc[r].x = fmaf(xv.w, wr[3].x, acc[r].x);
            acc[r].y = fmaf(xv.w, wr[3].y, acc[r].y);
            acc[r].z = fmaf(xv.w, wr[3].z, acc[r].z);
            acc[r].w = fmaf(xv.w, wr[3].w, acc[r].w);
        }
    }
    float4 asv = ((const float4*)a_src)[jg];
    float4 adv = ((const float4*)a_dst)[jg];
#pragma unroll
    for (int r = 0; r < 8; ++r) {
        int n = n0 + ng * 8 + r;
        float ps = acc[r].x * asv.x + acc[r].y * asv.y + acc[r].z * asv.z + acc[r].w * asv.w;
        float pd = acc[r].x * adv.x + acc[r].y * adv.y + acc[r].z * adv.z + acc[r].w * adv.w;
        ps += __shfl_xor(ps, 1); pd += __shfl_xor(pd, 1);
        ps += __shfl_xor(ps, 2); pd += __shfl_xor(pd, 2);
        ps += __shfl_xor(ps, 4); pd += __shfl_xor(pd, 4);
        if (n < NN) {
            ((float4*)xw)[(size_t)n * 32 + jg] = acc[r];
            if ((jg & 7) == 0) {
                int h = jg >> 3;
                as_[n * HH + h] = ps;
                ad_[n * HH + h] = pd;
            }
        }
    }
}

// ---------------- fused segment softmax + aggregate + bias + ELU ----------------
#define SWSTR 66
__global__ __launch_bounds__(256) void aggregate(
    const int* __restrict__ esrc, const int* __restrict__ row_start,
    const float* __restrict__ as_, const float* __restrict__ ad_,
    const float* __restrict__ xw, const float* __restrict__ bias,
    float* __restrict__ out) {
    __shared__ float2 sw_all[4][4 * SWSTR];
    int wid = (int)(threadIdx.x >> 6);
    int node = blockIdx.x * 4 + wid;
    if (node >= NN) return;
    int lane = threadIdx.x & 63;
    float2* sw = &sw_all[wid][0];
    int beg = row_start[node];
    int end = row_start[node + 1];
    float4 ad = ((const float4*)ad_)[node];

    float m0 = -1e30f, m1 = -1e30f, m2 = -1e30f, m3 = -1e30f;
    for (int i = beg + lane; i < end; i += 64) {
        float4 av = ((const float4*)as_)[esrc[i]];
        m0 = fmaxf(m0, lrelu(av.x + ad.x));
        m1 = fmaxf(m1, lrelu(av.y + ad.y));
        m2 = fmaxf(m2, lrelu(av.z + ad.z));
        m3 = fmaxf(m3, lrelu(av.w + ad.w));
    }
#pragma unroll
    for (int off = 32; off; off >>= 1) {
        m0 = fmaxf(m0, __shfl_xor(m0, off));
        m1 = fmaxf(m1, __shfl_xor(m1, off));
        m2 = fmaxf(m2, __shfl_xor(m2, off));
        m3 = fmaxf(m3, __shfl_xor(m3, off));
    }

    int c = lane & 31;
    int pair = lane >> 5;
    int h = c >> 3;
    float4 acc = make_float4(0.f, 0.f, 0.f, 0.f);
    float d0 = 0.f, d1 = 0.f, d2 = 0.f, d3 = 0.f;
    for (int base = beg; base < end; base += 64) {
        int i = base + lane;
        int cnt = end - base; if (cnt > 64) cnt = 64;
        if (i < end) {
            int s = esrc[i];
            float4 av = ((const float4*)as_)[s];
            float w0 = __expf(lrelu(av.x + ad.x) - m0);
            float w1 = __expf(lrelu(av.y + ad.y) - m1);
            float w2 = __expf(lrelu(av.z + ad.z) - m2);
            float w3 = __expf(lrelu(av.w + ad.w) - m3);
            d0 += w0; d1 += w1; d2 += w2; d3 += w3;
            float sf = __int_as_float(s);
            sw[0 * SWSTR + lane] = make_float2(sf, w0);
            sw[1 * SWSTR + lane] = make_float2(sf, w1);
            sw[2 * SWSTR + lane] = make_float2(sf, w2);
            sw[3 * SWSTR + lane] = make_float2(sf, w3);
        }
        int iters = (cnt + 1) >> 1;
        for (int it = 0; it < iters; ++it) {
            int j = 2 * it + pair;
            float2 swv = sw[h * SWSTR + j];
            float wj = (j < cnt) ? swv.y : 0.f;
            int sj = (j < cnt) ? __float_as_int(swv.x) : 0;
            float4 v = ((const float4*)xw)[(size_t)sj * 32 + c];
            acc.x = fmaf(wj, v.x, acc.x);
            acc.y = fmaf(wj, v.y, acc.y);
            acc.z = fmaf(wj, v.z, acc.z);
            acc.w = fmaf(wj, v.w, acc.w);
        }
    }
    acc.x += __shfl_xor(acc.x, 32);
    acc.y += __shfl_xor(acc.y, 32);
    acc.z += __shfl_xor(acc.z, 32);
    acc.w += __shfl_xor(acc.w, 32);
#pragma unroll
    for (int off = 32; off; off >>= 1) {
        d0 += __shfl_xor(d0, off);
        d1 += __shfl_xor(d1, off);
        d2 += __shfl_xor(d2, off);
        d3 += __shfl_xor(d3, off);
    }
    if (lane < 32) {
        float dn = h == 0 ? d0 : (h == 1 ? d1 : (h == 2 ? d2 : d3));
        float4 bb = ((const float4*)bias)[c];
        float4 o;
        o.x = acc.x / dn + bb.x;
        o.y = acc.y / dn + bb.y;
        o.z = acc.z / dn + bb.z;
        o.w = acc.w / dn + bb.w;
        o.x = o.x > 0.f ? o.x : expm1f(o.x);
        o.y = o.y > 0.f ? o.y : expm1f(o.y);
        o.z = o.z > 0.f ? o.z : expm1f(o.z);
        o.w = o.w > 0.f ? o.w : expm1f(o.w);
        ((float4*)out)[(size_t)node * 32 + c] = o;
    }
}

// ---------------- pooling + head ----------------
__global__ __launch_bounds__(128) void pool(
    const float* __restrict__ h1, const int* __restrict__ batch,
    float* __restrict__ sums, float* __restrict__ cnts) {
    int j = threadIdx.x;
    int n0 = blockIdx.x * 64;
    int n1 = n0 + 64; if (n1 > NN) n1 = NN;
    if (n0 >= NN) return;
    int cur = batch[n0];
    float local = 0.f;
    int cnt = 0;
    for (int n = n0; n < n1; ++n) {
        int g = batch[n];
        if (g != cur) {
            atomicAdd(&sums[cur * HC + j], local);
            if (j == 0) atomicAdd(&cnts[cur], (float)cnt);
            local = 0.f; cnt = 0; cur = g;
        }
        local += h1[(size_t)n * HC + j];
        ++cnt;
    }
    atomicAdd(&sums[cur * HC + j], local);
    if (j == 0) atomicAdd(&cnts[cur], (float)cnt);
}

__global__ __launch_bounds__(128) void head_out(
    const float* __restrict__ sums, const float* __restrict__ cnts,
    const float* __restrict__ lin_w, const float* __restrict__ lin_b,
    float* __restrict__ out) {
    int g = blockIdx.x;
    int j = threadIdx.x;
    float c = cnts[g];
    c = c > 1.f ? c : 1.f;
    float v = sums[g * HC + j] / c * lin_w[j];
    __shared__ float red[HC];
    red[j] = v;
    __syncthreads();
    for (int off = 64; off > 0; off >>= 1) {
        if (j < off) red[j] += red[j + off];
        __syncthreads();
    }
    if (j == 0) out[g] = red[0] + lin_b[0];
}

extern "C" void kernel_launch(void* const* d_in, const int* in_sizes, int n_in,
                              void* d_out, int out_size, void* d_ws, size_t ws_size,
                              hipStream_t stream) {
    const float* x   = (const float*)d_in[0];
    const int*   ei  = (const int*)d_in[1];
    const int*   bat = (const int*)d_in[2];
    const float* W0  = (const float*)d_in[3];
    const float* as0 = (const float*)d_in[4];
    const float* ad0 = (const float*)d_in[5];
    const float* b0  = (const float*)d_in[6];
    const float* W1  = (const float*)d_in[7];
    const float* as1 = (const float*)d_in[8];
    const float* ad1 = (const float*)d_in[9];
    const float* b1  = (const float*)d_in[10];
    const float* lw  = (const float*)d_in[11];
    const float* lb  = (const float*)d_in[12];
    float* out = (float*)d_out;

    char* w = (char*)d_ws;
    float* xw  = (float*)w;  w += (size_t)NN * HC * 4;
    float* h0  = (float*)w;  w += (size_t)NN * HC * 4;
    float* as_ = (float*)w;  w += (size_t)NN * HH * 4;
    float* ad_ = (float*)w;  w += (size_t)NN * HH * 4;
    int* deg       = (int*)w; w += (size_t)NN * 4;
    int* row_start = (int*)w; w += (size_t)(NN + 1) * 4;
    int* cursor    = (int*)w; w += (size_t)NN * 4;
    int* esrc      = (int*)w; w += (size_t)NEDGE * 4;
    float* sums = (float*)w; w += (size_t)GG * HC * 4;
    float* cnts = (float*)w; w += (size_t)GG * 4;

    const int gb = (NN + GMT - 1) / GMT;
    const int ab = (NN + 3) / 4;

    // ---- CSR build (shared by both layers) ----
    hipMemsetAsync(deg, 0, (size_t)NN * 4, stream);
    hist2<<<NXCD * HB, 256, 0, stream>>>(ei, deg);
    scan_deg<<<1, 1024, 0, stream>>>(deg, row_start, cursor);
    scatter2<<<NXCD * SB, 256, 0, stream>>>(ei, cursor, esrc);

    // ---- layer 0 ----
    gemm_alpha<<<gb, 256, 0, stream>>>(x, W0, as0, ad0, xw, as_, ad_);
    aggregate<<<ab, 256, 0, stream>>>(esrc, row_start, as_, ad_, xw, b0, h0);

    // ---- layer 1 ----
    gemm_alpha<<<gb, 256, 0, stream>>>(h0, W1, as1, ad1, xw, as_, ad_);
    aggregate<<<ab, 256, 0, stream>>>(esrc, row_start, as_, ad_, xw, b1, h0);

    // ---- pool + head ----
    hipMemsetAsync(sums, 0, ((size_t)GG * HC + GG) * 4, stream);
    pool<<<(NN + 63) / 64, 128, 0, stream>>>(h0, bat, sums, cnts);
    head_out<<<GG, 128, 0, stream>>>(sums, cnts, lw, lb, out);
}

// Round 5
// 651.091 us; speedup vs baseline: 1.2597x; 1.2597x over previous
//
#include <hip/hip_runtime.h>
#include <hip/hip_bf16.h>

#define NN 50000
#define EE 1600000
#define NEDGE (EE + NN)   // with self loops
#define HH 4
#define HC 128
#define GG 64
#define GMT 64            // nodes per gemm block
#define NXCD 8
#define RNG (NN / NXCD)   // 6250 nodes per XCD group
#define SB 32             // scatter sub-blocks per group

__device__ __forceinline__ float lrelu(float x) { return x > 0.f ? x : 0.2f * x; }

// ---------------- CSR build ----------------
// hist: flat, real edges only (self-loops accounted as +1 in the scan)
__global__ __launch_bounds__(256) void hist(const int* __restrict__ ei, int* __restrict__ deg) {
    int i = blockIdx.x * 256 + threadIdx.x;
    if (i >= EE) return;
    atomicAdd(&deg[ei[EE + i]], 1);
}

// one block; deg[i]+1 accounts for the self loop; writes row_start AND cursor
__global__ __launch_bounds__(1024) void scan_deg(const int* __restrict__ deg,
                                                 int* __restrict__ row_start,
                                                 int* __restrict__ cursor) {
    __shared__ int sums[1024];
    int t = threadIdx.x;
    const int per = (NN + 1023) / 1024;
    int lo = t * per, hi = lo + per; if (hi > NN) hi = NN;
    int s = 0;
    for (int i = lo; i < hi; ++i) s += deg[i] + 1;
    sums[t] = s;
    __syncthreads();
    for (int off = 1; off < 1024; off <<= 1) {
        int v = (t >= off) ? sums[t - off] : 0;
        __syncthreads();
        sums[t] += v;
        __syncthreads();
    }
    int run = sums[t] - s;
    for (int i = lo; i < hi; ++i) {
        row_start[i] = run;
        cursor[i] = run;
        run += deg[i] + 1;
    }
    if (t == 0) row_start[NN] = NEDGE;
}

// XCD-range-partitioned scatter: group g owns dst range [g*RNG,(g+1)*RNG),
// so all esrc writes of a group land in one contiguous slice (full-line
// dirty writebacks in one XCD's L2 instead of 15x write amplification).
__global__ __launch_bounds__(256) void scatter2(const int* __restrict__ ei, int* __restrict__ cursor,
                                                int* __restrict__ esrc) {
    int g = blockIdx.x & (NXCD - 1);
    int sub = blockIdx.x >> 3;
    int t = threadIdx.x;
    int lo = g * RNG;
    const int per = (EE + SB - 1) / SB;
    int e0 = sub * per, e1 = e0 + per; if (e1 > EE) e1 = EE;
    for (int i = e0 + t; i < e1; i += 256) {
        int d = ei[EE + i];
        unsigned r = (unsigned)(d - lo);
        if (r < RNG) {
            int s = ei[i];
            int pos = atomicAdd(&cursor[d], 1);
            esrc[pos] = s;
        }
    }
    // self loops for this group's node slice
    const int perN = (RNG + SB - 1) / SB;
    int n0 = lo + sub * perN, n1 = n0 + perN; if (n1 > lo + RNG) n1 = lo + RNG;
    for (int n = n0 + t; n < n1; n += 256) {
        int pos = atomicAdd(&cursor[n], 1);
        esrc[pos] = n;
    }
}

// ---------------- GEMM (X @ W) + per-head alpha dots ----------------
__global__ __launch_bounds__(256) void gemm_alpha(
    const float* __restrict__ X, const float* __restrict__ W,
    const float* __restrict__ a_src, const float* __restrict__ a_dst,
    float* __restrict__ xw, float* __restrict__ as_, float* __restrict__ ad_) {
    __shared__ float xs[GMT][HC + 4];
    int tid = threadIdx.x;
    int n0 = blockIdx.x * GMT;
    for (int i = tid; i < GMT * (HC / 4); i += 256) {
        int r = i >> 5, c4 = i & 31;
        int n = n0 + r;
        float4 v = (n < NN) ? ((const float4*)X)[(size_t)n * 32 + c4]
                            : make_float4(0.f, 0.f, 0.f, 0.f);
        *(float4*)&xs[r][c4 * 4] = v;
    }
    __syncthreads();

    int jg = tid & 31;
    int ng = tid >> 5;
    float4 acc[8] = {};
    for (int k = 0; k < HC; k += 4) {
        float4 wr[4];
#pragma unroll
        for (int dk = 0; dk < 4; ++dk) wr[dk] = ((const float4*)W)[(k + dk) * 32 + jg];
#pragma unroll
        for (int r = 0; r < 8; ++r) {
            float4 xv = *(const float4*)&xs[ng * 8 + r][k];
            acc[r].x = fmaf(xv.x, wr[0].x, acc[r].x);
            acc[r].y = fmaf(xv.x, wr[0].y, acc[r].y);
            acc[r].z = fmaf(xv.x, wr[0].z, acc[r].z);
            acc[r].w = fmaf(xv.x, wr[0].w, acc[r].w);
            acc[r].x = fmaf(xv.y, wr[1].x, acc[r].x);
            acc[r].y = fmaf(xv.y, wr[1].y, acc[r].y);
            acc[r].z = fmaf(xv.y, wr[1].z, acc[r].z);
            acc[r].w = fmaf(xv.y, wr[1].w, acc[r].w);
            acc[r].x = fmaf(xv.z, wr[2].x, acc[r].x);
            acc[r].y = fmaf(xv.z, wr[2].y, acc[r].y);
            acc[r].z = fmaf(xv.z, wr[2].z, acc[r].z);
            acc[r].w = fmaf(xv.z, wr[2].w, acc[r].w);
            acc[r].x = fmaf(xv.w, wr[3].x, acc[r].x);
            acc[r].y = fmaf(xv.w, wr[3].y, acc[r].y);
            acc[r].z = fmaf(xv.w, wr[3].z, acc[r].z);
            acc[r].w = fmaf(xv.w, wr[3].w, acc[r].w);
        }
    }
    float4 asv = ((const float4*)a_src)[jg];
    float4 adv = ((const float4*)a_dst)[jg];
#pragma unroll
    for (int r = 0; r < 8; ++r) {
        int n = n0 + ng * 8 + r;
        float ps = acc[r].x * asv.x + acc[r].y * asv.y + acc[r].z * asv.z + acc[r].w * asv.w;
        float pd = acc[r].x * adv.x + acc[r].y * adv.y + acc[r].z * adv.z + acc[r].w * adv.w;
        ps += __shfl_xor(ps, 1); pd += __shfl_xor(pd, 1);
        ps += __shfl_xor(ps, 2); pd += __shfl_xor(pd, 2);
        ps += __shfl_xor(ps, 4); pd += __shfl_xor(pd, 4);
        if (n < NN) {
            ((float4*)xw)[(size_t)n * 32 + jg] = acc[r];
            if ((jg & 7) == 0) {
                int h = jg >> 3;
                as_[n * HH + h] = ps;
                ad_[n * HH + h] = pd;
            }
        }
    }
}

// ---------------- fused segment softmax + aggregate + bias + ELU ----------------
#define SWSTR 66
__global__ __launch_bounds__(256) void aggregate(
    const int* __restrict__ esrc, const int* __restrict__ row_start,
    const float* __restrict__ as_, const float* __restrict__ ad_,
    const float* __restrict__ xw, const float* __restrict__ bias,
    float* __restrict__ out) {
    __shared__ float2 sw_all[4][4 * SWSTR];
    int wid = (int)(threadIdx.x >> 6);
    int node = blockIdx.x * 4 + wid;
    if (node >= NN) return;
    int lane = threadIdx.x & 63;
    float2* sw = &sw_all[wid][0];
    int beg = row_start[node];
    int end = row_start[node + 1];
    float4 ad = ((const float4*)ad_)[node];

    float m0 = -1e30f, m1 = -1e30f, m2 = -1e30f, m3 = -1e30f;
    for (int i = beg + lane; i < end; i += 64) {
        float4 av = ((const float4*)as_)[esrc[i]];
        m0 = fmaxf(m0, lrelu(av.x + ad.x));
        m1 = fmaxf(m1, lrelu(av.y + ad.y));
        m2 = fmaxf(m2, lrelu(av.z + ad.z));
        m3 = fmaxf(m3, lrelu(av.w + ad.w));
    }
#pragma unroll
    for (int off = 32; off; off >>= 1) {
        m0 = fmaxf(m0, __shfl_xor(m0, off));
        m1 = fmaxf(m1, __shfl_xor(m1, off));
        m2 = fmaxf(m2, __shfl_xor(m2, off));
        m3 = fmaxf(m3, __shfl_xor(m3, off));
    }

    int c = lane & 31;
    int pair = lane >> 5;
    int h = c >> 3;
    float4 acc = make_float4(0.f, 0.f, 0.f, 0.f);
    float d0 = 0.f, d1 = 0.f, d2 = 0.f, d3 = 0.f;
    for (int base = beg; base < end; base += 64) {
        int i = base + lane;
        int cnt = end - base; if (cnt > 64) cnt = 64;
        if (i < end) {
            int s = esrc[i];
            float4 av = ((const float4*)as_)[s];
            float w0 = __expf(lrelu(av.x + ad.x) - m0);
            float w1 = __expf(lrelu(av.y + ad.y) - m1);
            float w2 = __expf(lrelu(av.z + ad.z) - m2);
            float w3 = __expf(lrelu(av.w + ad.w) - m3);
            d0 += w0; d1 += w1; d2 += w2; d3 += w3;
            float sf = __int_as_float(s);
            sw[0 * SWSTR + lane] = make_float2(sf, w0);
            sw[1 * SWSTR + lane] = make_float2(sf, w1);
            sw[2 * SWSTR + lane] = make_float2(sf, w2);
            sw[3 * SWSTR + lane] = make_float2(sf, w3);
        }
        int iters = (cnt + 1) >> 1;
        for (int it = 0; it < iters; ++it) {
            int j = 2 * it + pair;
            float2 swv = sw[h * SWSTR + j];
            float wj = (j < cnt) ? swv.y : 0.f;
            int sj = (j < cnt) ? __float_as_int(swv.x) : 0;
            float4 v = ((const float4*)xw)[(size_t)sj * 32 + c];
            acc.x = fmaf(wj, v.x, acc.x);
            acc.y = fmaf(wj, v.y, acc.y);
            acc.z = fmaf(wj, v.z, acc.z);
            acc.w = fmaf(wj, v.w, acc.w);
        }
    }
    acc.x += __shfl_xor(acc.x, 32);
    acc.y += __shfl_xor(acc.y, 32);
    acc.z += __shfl_xor(acc.z, 32);
    acc.w += __shfl_xor(acc.w, 32);
#pragma unroll
    for (int off = 32; off; off >>= 1) {
        d0 += __shfl_xor(d0, off);
        d1 += __shfl_xor(d1, off);
        d2 += __shfl_xor(d2, off);
        d3 += __shfl_xor(d3, off);
    }
    if (lane < 32) {
        float dn = h == 0 ? d0 : (h == 1 ? d1 : (h == 2 ? d2 : d3));
        float4 bb = ((const float4*)bias)[c];
        float4 o;
        o.x = acc.x / dn + bb.x;
        o.y = acc.y / dn + bb.y;
        o.z = acc.z / dn + bb.z;
        o.w = acc.w / dn + bb.w;
        o.x = o.x > 0.f ? o.x : expm1f(o.x);
        o.y = o.y > 0.f ? o.y : expm1f(o.y);
        o.z = o.z > 0.f ? o.z : expm1f(o.z);
        o.w = o.w > 0.f ? o.w : expm1f(o.w);
        ((float4*)out)[(size_t)node * 32 + c] = o;
    }
}

// ---------------- pooling + head ----------------
__global__ __launch_bounds__(128) void pool(
    const float* __restrict__ h1, const int* __restrict__ batch,
    float* __restrict__ sums, float* __restrict__ cnts) {
    int j = threadIdx.x;
    int n0 = blockIdx.x * 64;
    int n1 = n0 + 64; if (n1 > NN) n1 = NN;
    if (n0 >= NN) return;
    int cur = batch[n0];
    float local = 0.f;
    int cnt = 0;
    for (int n = n0; n < n1; ++n) {
        int g = batch[n];
        if (g != cur) {
            atomicAdd(&sums[cur * HC + j], local);
            if (j == 0) atomicAdd(&cnts[cur], (float)cnt);
            local = 0.f; cnt = 0; cur = g;
        }
        local += h1[(size_t)n * HC + j];
        ++cnt;
    }
    atomicAdd(&sums[cur * HC + j], local);
    if (j == 0) atomicAdd(&cnts[cur], (float)cnt);
}

__global__ __launch_bounds__(128) void head_out(
    const float* __restrict__ sums, const float* __restrict__ cnts,
    const float* __restrict__ lin_w, const float* __restrict__ lin_b,
    float* __restrict__ out) {
    int g = blockIdx.x;
    int j = threadIdx.x;
    float c = cnts[g];
    c = c > 1.f ? c : 1.f;
    float v = sums[g * HC + j] / c * lin_w[j];
    __shared__ float red[HC];
    red[j] = v;
    __syncthreads();
    for (int off = 64; off > 0; off >>= 1) {
        if (j < off) red[j] += red[j + off];
        __syncthreads();
    }
    if (j == 0) out[g] = red[0] + lin_b[0];
}

extern "C" void kernel_launch(void* const* d_in, const int* in_sizes, int n_in,
                              void* d_out, int out_size, void* d_ws, size_t ws_size,
                              hipStream_t stream) {
    const float* x   = (const float*)d_in[0];
    const int*   ei  = (const int*)d_in[1];
    const int*   bat = (const int*)d_in[2];
    const float* W0  = (const float*)d_in[3];
    const float* as0 = (const float*)d_in[4];
    const float* ad0 = (const float*)d_in[5];
    const float* b0  = (const float*)d_in[6];
    const float* W1  = (const float*)d_in[7];
    const float* as1 = (const float*)d_in[8];
    const float* ad1 = (const float*)d_in[9];
    const float* b1  = (const float*)d_in[10];
    const float* lw  = (const float*)d_in[11];
    const float* lb  = (const float*)d_in[12];
    float* out = (float*)d_out;

    char* w = (char*)d_ws;
    float* xw  = (float*)w;  w += (size_t)NN * HC * 4;
    float* h0  = (float*)w;  w += (size_t)NN * HC * 4;
    float* as_ = (float*)w;  w += (size_t)NN * HH * 4;
    float* ad_ = (float*)w;  w += (size_t)NN * HH * 4;
    int* deg       = (int*)w; w += (size_t)NN * 4;
    int* row_start = (int*)w; w += (size_t)(NN + 1) * 4;
    int* cursor    = (int*)w; w += (size_t)NN * 4;
    int* esrc      = (int*)w; w += (size_t)NEDGE * 4;
    float* sums = (float*)w; w += (size_t)GG * HC * 4;
    float* cnts = (float*)w; w += (size_t)GG * 4;

    const int gb = (NN + GMT - 1) / GMT;
    const int ab = (NN + 3) / 4;

    // ---- CSR build (shared by both layers) ----
    hipMemsetAsync(deg, 0, (size_t)NN * 4, stream);
    hist<<<(EE + 255) / 256, 256, 0, stream>>>(ei, deg);
    scan_deg<<<1, 1024, 0, stream>>>(deg, row_start, cursor);
    scatter2<<<NXCD * SB, 256, 0, stream>>>(ei, cursor, esrc);

    // ---- layer 0 ----
    gemm_alpha<<<gb, 256, 0, stream>>>(x, W0, as0, ad0, xw, as_, ad_);
    aggregate<<<ab, 256, 0, stream>>>(esrc, row_start, as_, ad_, xw, b0, h0);

    // ---- layer 1 ----
    gemm_alpha<<<gb, 256, 0, stream>>>(h0, W1, as1, ad1, xw, as_, ad_);
    aggregate<<<ab, 256, 0, stream>>>(esrc, row_start, as_, ad_, xw, b1, h0);

    // ---- pool + head ----
    hipMemsetAsync(sums, 0, ((size_t)GG * HC + GG) * 4, stream);
    pool<<<(NN + 63) / 64, 128, 0, stream>>>(h0, bat, sums, cnts);
    head_out<<<GG, 128, 0, stream>>>(sums, cnts, lw, lb, out);
}

// Round 6
// 578.719 us; speedup vs baseline: 1.4172x; 1.1251x over previous
//
#include <hip/hip_runtime.h>
#include <hip/hip_bf16.h>

#define NN 50000
#define EE 1600000
#define NEDGE (EE + NN)   // with self loops
#define HH 4
#define HC 128
#define GG 64
#define GMT 64            // nodes per gemm block
#define NXCD 8
#define RNG (NN / NXCD)   // 6250 nodes per XCD group
#define SB 256            // scatter sub-blocks per group (2048 blocks total)

__device__ __forceinline__ float lrelu(float x) { return x > 0.f ? x : 0.2f * x; }

// ---------------- CSR build ----------------
// hist: flat, real edges only (self-loops accounted as +1 in the scan)
__global__ __launch_bounds__(256) void hist(const int* __restrict__ ei, int* __restrict__ deg) {
    int i = blockIdx.x * 256 + threadIdx.x;
    if (i >= EE) return;
    atomicAdd(&deg[ei[EE + i]], 1);
}

// one block; deg[i]+1 accounts for the self loop; writes row_start AND cursor
__global__ __launch_bounds__(1024) void scan_deg(const int* __restrict__ deg,
                                                 int* __restrict__ row_start,
                                                 int* __restrict__ cursor) {
    __shared__ int sums[1024];
    int t = threadIdx.x;
    const int per = (NN + 1023) / 1024;
    int lo = t * per, hi = lo + per; if (hi > NN) hi = NN;
    int s = 0;
    for (int i = lo; i < hi; ++i) s += deg[i] + 1;
    sums[t] = s;
    __syncthreads();
    for (int off = 1; off < 1024; off <<= 1) {
        int v = (t >= off) ? sums[t - off] : 0;
        __syncthreads();
        sums[t] += v;
        __syncthreads();
    }
    int run = sums[t] - s;
    for (int i = lo; i < hi; ++i) {
        row_start[i] = run;
        cursor[i] = run;
        run += deg[i] + 1;
    }
    if (t == 0) row_start[NN] = NEDGE;
}

// XCD-range-partitioned scatter: group g = blockIdx&7 owns dst range
// [g*RNG,(g+1)*RNG) so cursor atomics and esrc writes stay XCD-local.
__global__ __launch_bounds__(256) void scatter2(const int* __restrict__ ei, int* __restrict__ cursor,
                                                int* __restrict__ esrc) {
    int g = blockIdx.x & (NXCD - 1);
    int sub = blockIdx.x >> 3;
    int t = threadIdx.x;
    int lo = g * RNG;
    const int per = (EE + SB - 1) / SB;
    int e0 = sub * per, e1 = e0 + per; if (e1 > EE) e1 = EE;
    for (int i = e0 + t; i < e1; i += 256) {
        int d = ei[EE + i];
        unsigned r = (unsigned)(d - lo);
        if (r < RNG) {
            int s = ei[i];
            int pos = atomicAdd(&cursor[d], 1);
            esrc[pos] = s;
        }
    }
    // self loops for this group's node slice
    const int perN = (RNG + SB - 1) / SB;
    int n0 = lo + sub * perN, n1 = n0 + perN; if (n1 > lo + RNG) n1 = lo + RNG;
    for (int n = n0 + t; n < n1; n += 256) {
        int pos = atomicAdd(&cursor[n], 1);
        esrc[pos] = n;
    }
}

// ---------------- GEMM (X @ W) + per-head alpha dots ----------------
__global__ __launch_bounds__(256) void gemm_alpha(
    const float* __restrict__ X, const float* __restrict__ W,
    const float* __restrict__ a_src, const float* __restrict__ a_dst,
    float* __restrict__ xw, float* __restrict__ as_, float* __restrict__ ad_) {
    __shared__ float xs[GMT][HC + 4];
    int tid = threadIdx.x;
    int n0 = blockIdx.x * GMT;
    for (int i = tid; i < GMT * (HC / 4); i += 256) {
        int r = i >> 5, c4 = i & 31;
        int n = n0 + r;
        float4 v = (n < NN) ? ((const float4*)X)[(size_t)n * 32 + c4]
                            : make_float4(0.f, 0.f, 0.f, 0.f);
        *(float4*)&xs[r][c4 * 4] = v;
    }
    __syncthreads();

    int jg = tid & 31;
    int ng = tid >> 5;
    float4 acc[8] = {};
    for (int k = 0; k < HC; k += 4) {
        float4 wr[4];
#pragma unroll
        for (int dk = 0; dk < 4; ++dk) wr[dk] = ((const float4*)W)[(k + dk) * 32 + jg];
#pragma unroll
        for (int r = 0; r < 8; ++r) {
            float4 xv = *(const float4*)&xs[ng * 8 + r][k];
            acc[r].x = fmaf(xv.x, wr[0].x, acc[r].x);
            acc[r].y = fmaf(xv.x, wr[0].y, acc[r].y);
            acc[r].z = fmaf(xv.x, wr[0].z, acc[r].z);
            acc[r].w = fmaf(xv.x, wr[0].w, acc[r].w);
            acc[r].x = fmaf(xv.y, wr[1].x, acc[r].x);
            acc[r].y = fmaf(xv.y, wr[1].y, acc[r].y);
            acc[r].z = fmaf(xv.y, wr[1].z, acc[r].z);
            acc[r].w = fmaf(xv.y, wr[1].w, acc[r].w);
            acc[r].x = fmaf(xv.z, wr[2].x, acc[r].x);
            acc[r].y = fmaf(xv.z, wr[2].y, acc[r].y);
            acc[r].z = fmaf(xv.z, wr[2].z, acc[r].z);
            acc[r].w = fmaf(xv.z, wr[2].w, acc[r].w);
            acc[r].x = fmaf(xv.w, wr[3].x, acc[r].x);
            acc[r].y = fmaf(xv.w, wr[3].y, acc[r].y);
            acc[r].z = fmaf(xv.w, wr[3].z, acc[r].z);
            acc[r].w = fmaf(xv.w, wr[3].w, acc[r].w);
        }
    }
    float4 asv = ((const float4*)a_src)[jg];
    float4 adv = ((const float4*)a_dst)[jg];
#pragma unroll
    for (int r = 0; r < 8; ++r) {
        int n = n0 + ng * 8 + r;
        float ps = acc[r].x * asv.x + acc[r].y * asv.y + acc[r].z * asv.z + acc[r].w * asv.w;
        float pd = acc[r].x * adv.x + acc[r].y * adv.y + acc[r].z * adv.z + acc[r].w * adv.w;
        ps += __shfl_xor(ps, 1); pd += __shfl_xor(pd, 1);
        ps += __shfl_xor(ps, 2); pd += __shfl_xor(pd, 2);
        ps += __shfl_xor(ps, 4); pd += __shfl_xor(pd, 4);
        if (n < NN) {
            ((float4*)xw)[(size_t)n * 32 + jg] = acc[r];
            if ((jg & 7) == 0) {
                int h = jg >> 3;
                as_[n * HH + h] = ps;
                ad_[n * HH + h] = pd;
            }
        }
    }
}

// ---------------- fused segment softmax + aggregate + bias + ELU ----------------
#define SWSTR 66
__global__ __launch_bounds__(256) void aggregate(
    const int* __restrict__ esrc, const int* __restrict__ row_start,
    const float* __restrict__ as_, const float* __restrict__ ad_,
    const float* __restrict__ xw, const float* __restrict__ bias,
    float* __restrict__ out) {
    __shared__ float2 sw_all[4][4 * SWSTR];
    int wid = (int)(threadIdx.x >> 6);
    int node = blockIdx.x * 4 + wid;
    if (node >= NN) return;
    int lane = threadIdx.x & 63;
    float2* sw = &sw_all[wid][0];
    int beg = row_start[node];
    int end = row_start[node + 1];
    float4 ad = ((const float4*)ad_)[node];

    float m0 = -1e30f, m1 = -1e30f, m2 = -1e30f, m3 = -1e30f;
    for (int i = beg + lane; i < end; i += 64) {
        float4 av = ((const float4*)as_)[esrc[i]];
        m0 = fmaxf(m0, lrelu(av.x + ad.x));
        m1 = fmaxf(m1, lrelu(av.y + ad.y));
        m2 = fmaxf(m2, lrelu(av.z + ad.z));
        m3 = fmaxf(m3, lrelu(av.w + ad.w));
    }
#pragma unroll
    for (int off = 32; off; off >>= 1) {
        m0 = fmaxf(m0, __shfl_xor(m0, off));
        m1 = fmaxf(m1, __shfl_xor(m1, off));
        m2 = fmaxf(m2, __shfl_xor(m2, off));
        m3 = fmaxf(m3, __shfl_xor(m3, off));
    }

    int c = lane & 31;
    int pair = lane >> 5;
    int h = c >> 3;
    float4 acc = make_float4(0.f, 0.f, 0.f, 0.f);
    float d0 = 0.f, d1 = 0.f, d2 = 0.f, d3 = 0.f;
    for (int base = beg; base < end; base += 64) {
        int i = base + lane;
        int cnt = end - base; if (cnt > 64) cnt = 64;
        if (i < end) {
            int s = esrc[i];
            float4 av = ((const float4*)as_)[s];
            float w0 = __expf(lrelu(av.x + ad.x) - m0);
            float w1 = __expf(lrelu(av.y + ad.y) - m1);
            float w2 = __expf(lrelu(av.z + ad.z) - m2);
            float w3 = __expf(lrelu(av.w + ad.w) - m3);
            d0 += w0; d1 += w1; d2 += w2; d3 += w3;
            float sf = __int_as_float(s);
            sw[0 * SWSTR + lane] = make_float2(sf, w0);
            sw[1 * SWSTR + lane] = make_float2(sf, w1);
            sw[2 * SWSTR + lane] = make_float2(sf, w2);
            sw[3 * SWSTR + lane] = make_float2(sf, w3);
        }
        int iters = (cnt + 1) >> 1;
        for (int it = 0; it < iters; ++it) {
            int j = 2 * it + pair;
            float2 swv = sw[h * SWSTR + j];
            float wj = (j < cnt) ? swv.y : 0.f;
            int sj = (j < cnt) ? __float_as_int(swv.x) : 0;
            float4 v = ((const float4*)xw)[(size_t)sj * 32 + c];
            acc.x = fmaf(wj, v.x, acc.x);
            acc.y = fmaf(wj, v.y, acc.y);
            acc.z = fmaf(wj, v.z, acc.z);
            acc.w = fmaf(wj, v.w, acc.w);
        }
    }
    acc.x += __shfl_xor(acc.x, 32);
    acc.y += __shfl_xor(acc.y, 32);
    acc.z += __shfl_xor(acc.z, 32);
    acc.w += __shfl_xor(acc.w, 32);
#pragma unroll
    for (int off = 32; off; off >>= 1) {
        d0 += __shfl_xor(d0, off);
        d1 += __shfl_xor(d1, off);
        d2 += __shfl_xor(d2, off);
        d3 += __shfl_xor(d3, off);
    }
    if (lane < 32) {
        float dn = h == 0 ? d0 : (h == 1 ? d1 : (h == 2 ? d2 : d3));
        float4 bb = ((const float4*)bias)[c];
        float4 o;
        o.x = acc.x / dn + bb.x;
        o.y = acc.y / dn + bb.y;
        o.z = acc.z / dn + bb.z;
        o.w = acc.w / dn + bb.w;
        o.x = o.x > 0.f ? o.x : expm1f(o.x);
        o.y = o.y > 0.f ? o.y : expm1f(o.y);
        o.z = o.z > 0.f ? o.z : expm1f(o.z);
        o.w = o.w > 0.f ? o.w : expm1f(o.w);
        ((float4*)out)[(size_t)node * 32 + c] = o;
    }
}

// ---------------- pooling + head ----------------
__global__ __launch_bounds__(128) void pool(
    const float* __restrict__ h1, const int* __restrict__ batch,
    float* __restrict__ sums, float* __restrict__ cnts) {
    int j = threadIdx.x;
    int n0 = blockIdx.x * 64;
    int n1 = n0 + 64; if (n1 > NN) n1 = NN;
    if (n0 >= NN) return;
    int cur = batch[n0];
    float local = 0.f;
    int cnt = 0;
    for (int n = n0; n < n1; ++n) {
        int g = batch[n];
        if (g != cur) {
            atomicAdd(&sums[cur * HC + j], local);
            if (j == 0) atomicAdd(&cnts[cur], (float)cnt);
            local = 0.f; cnt = 0; cur = g;
        }
        local += h1[(size_t)n * HC + j];
        ++cnt;
    }
    atomicAdd(&sums[cur * HC + j], local);
    if (j == 0) atomicAdd(&cnts[cur], (float)cnt);
}

__global__ __launch_bounds__(128) void head_out(
    const float* __restrict__ sums, const float* __restrict__ cnts,
    const float* __restrict__ lin_w, const float* __restrict__ lin_b,
    float* __restrict__ out) {
    int g = blockIdx.x;
    int j = threadIdx.x;
    float c = cnts[g];
    c = c > 1.f ? c : 1.f;
    float v = sums[g * HC + j] / c * lin_w[j];
    __shared__ float red[HC];
    red[j] = v;
    __syncthreads();
    for (int off = 64; off > 0; off >>= 1) {
        if (j < off) red[j] += red[j + off];
        __syncthreads();
    }
    if (j == 0) out[g] = red[0] + lin_b[0];
}

extern "C" void kernel_launch(void* const* d_in, const int* in_sizes, int n_in,
                              void* d_out, int out_size, void* d_ws, size_t ws_size,
                              hipStream_t stream) {
    const float* x   = (const float*)d_in[0];
    const int*   ei  = (const int*)d_in[1];
    const int*   bat = (const int*)d_in[2];
    const float* W0  = (const float*)d_in[3];
    const float* as0 = (const float*)d_in[4];
    const float* ad0 = (const float*)d_in[5];
    const float* b0  = (const float*)d_in[6];
    const float* W1  = (const float*)d_in[7];
    const float* as1 = (const float*)d_in[8];
    const float* ad1 = (const float*)d_in[9];
    const float* b1  = (const float*)d_in[10];
    const float* lw  = (const float*)d_in[11];
    const float* lb  = (const float*)d_in[12];
    float* out = (float*)d_out;

    char* w = (char*)d_ws;
    float* xw  = (float*)w;  w += (size_t)NN * HC * 4;
    float* h0  = (float*)w;  w += (size_t)NN * HC * 4;
    float* as_ = (float*)w;  w += (size_t)NN * HH * 4;
    float* ad_ = (float*)w;  w += (size_t)NN * HH * 4;
    int* deg       = (int*)w; w += (size_t)NN * 4;
    int* row_start = (int*)w; w += (size_t)(NN + 1) * 4;
    int* cursor    = (int*)w; w += (size_t)NN * 4;
    int* esrc      = (int*)w; w += (size_t)NEDGE * 4;
    float* sums = (float*)w; w += (size_t)GG * HC * 4;
    float* cnts = (float*)w; w += (size_t)GG * 4;

    const int gb = (NN + GMT - 1) / GMT;
    const int ab = (NN + 3) / 4;

    // ---- CSR build (shared by both layers) ----
    hipMemsetAsync(deg, 0, (size_t)NN * 4, stream);
    hist<<<(EE + 255) / 256, 256, 0, stream>>>(ei, deg);
    scan_deg<<<1, 1024, 0, stream>>>(deg, row_start, cursor);
    scatter2<<<NXCD * SB, 256, 0, stream>>>(ei, cursor, esrc);

    // ---- layer 0 ----
    gemm_alpha<<<gb, 256, 0, stream>>>(x, W0, as0, ad0, xw, as_, ad_);
    aggregate<<<ab, 256, 0, stream>>>(esrc, row_start, as_, ad_, xw, b0, h0);

    // ---- layer 1 ----
    gemm_alpha<<<gb, 256, 0, stream>>>(h0, W1, as1, ad1, xw, as_, ad_);
    aggregate<<<ab, 256, 0, stream>>>(esrc, row_start, as_, ad_, xw, b1, h0);

    // ---- pool + head ----
    hipMemsetAsync(sums, 0, ((size_t)GG * HC + GG) * 4, stream);
    pool<<<(NN + 63) / 64, 128, 0, stream>>>(h0, bat, sums, cnts);
    head_out<<<GG, 128, 0, stream>>>(sums, cnts, lw, lb, out);
}

// Round 7
// 473.723 us; speedup vs baseline: 1.7313x; 1.2216x over previous
//
#include <hip/hip_runtime.h>
#include <hip/hip_bf16.h>

#define NN 50000
#define EE 1600000
#define NEDGE (EE + NN)   // with self loops
#define HH 4
#define HC 128
#define GG 64
#define GMT 64            // nodes per gemm block
#define NXCD 8
#define RNG (NN / NXCD)   // 6250 nodes per XCD group
#define SB 256            // scatter sub-blocks per group (2048 blocks total)

__device__ __forceinline__ float lrelu(float x) { return x > 0.f ? x : 0.2f * x; }

// round-to-nearest-even f32 -> bf16 (as u16), pack two into a uint
__device__ __forceinline__ unsigned packbf2(float a, float b) {
    unsigned ua = __float_as_uint(a);
    ua = (ua + 0x7fffu + ((ua >> 16) & 1u)) >> 16;
    unsigned ub = __float_as_uint(b);
    ub = (ub + 0x7fffu + ((ub >> 16) & 1u)) >> 16;
    return ua | (ub << 16);
}

// ---------------- CSR build ----------------
__global__ __launch_bounds__(256) void hist(const int* __restrict__ ei, int* __restrict__ deg) {
    int i = blockIdx.x * 256 + threadIdx.x;
    if (i >= EE) return;
    atomicAdd(&deg[ei[EE + i]], 1);
}

// one block; deg[i]+1 accounts for the self loop; writes row_start AND cursor
__global__ __launch_bounds__(1024) void scan_deg(const int* __restrict__ deg,
                                                 int* __restrict__ row_start,
                                                 int* __restrict__ cursor) {
    __shared__ int sums[1024];
    int t = threadIdx.x;
    const int per = (NN + 1023) / 1024;
    int lo = t * per, hi = lo + per; if (hi > NN) hi = NN;
    int s = 0;
    for (int i = lo; i < hi; ++i) s += deg[i] + 1;
    sums[t] = s;
    __syncthreads();
    for (int off = 1; off < 1024; off <<= 1) {
        int v = (t >= off) ? sums[t - off] : 0;
        __syncthreads();
        sums[t] += v;
        __syncthreads();
    }
    int run = sums[t] - s;
    for (int i = lo; i < hi; ++i) {
        row_start[i] = run;
        cursor[i] = run;
        run += deg[i] + 1;
    }
    if (t == 0) row_start[NN] = NEDGE;
}

// XCD-range-partitioned scatter (write locality), full-occupancy grid
__global__ __launch_bounds__(256) void scatter2(const int* __restrict__ ei, int* __restrict__ cursor,
                                                int* __restrict__ esrc) {
    int g = blockIdx.x & (NXCD - 1);
    int sub = blockIdx.x >> 3;
    int t = threadIdx.x;
    int lo = g * RNG;
    const int per = (EE + SB - 1) / SB;
    int e0 = sub * per, e1 = e0 + per; if (e1 > EE) e1 = EE;
    for (int i = e0 + t; i < e1; i += 256) {
        int d = ei[EE + i];
        unsigned r = (unsigned)(d - lo);
        if (r < RNG) {
            int s = ei[i];
            int pos = atomicAdd(&cursor[d], 1);
            esrc[pos] = s;
        }
    }
    const int perN = (RNG + SB - 1) / SB;
    int n0 = lo + sub * perN, n1 = n0 + perN; if (n1 > lo + RNG) n1 = lo + RNG;
    for (int n = n0 + t; n < n1; n += 256) {
        int pos = atomicAdd(&cursor[n], 1);
        esrc[pos] = n;
    }
}

// ---------------- GEMM (X @ W) + per-head alpha dots; bf16-packed output ----------------
__global__ __launch_bounds__(256) void gemm_alpha(
    const float* __restrict__ X, const float* __restrict__ W,
    const float* __restrict__ a_src, const float* __restrict__ a_dst,
    unsigned* __restrict__ xwb, float* __restrict__ as_, float* __restrict__ ad_) {
    __shared__ float xs[GMT][HC + 4];
    int tid = threadIdx.x;
    int n0 = blockIdx.x * GMT;
    for (int i = tid; i < GMT * (HC / 4); i += 256) {
        int r = i >> 5, c4 = i & 31;
        int n = n0 + r;
        float4 v = (n < NN) ? ((const float4*)X)[(size_t)n * 32 + c4]
                            : make_float4(0.f, 0.f, 0.f, 0.f);
        *(float4*)&xs[r][c4 * 4] = v;
    }
    __syncthreads();

    int jg = tid & 31;
    int ng = tid >> 5;
    float4 acc[8] = {};
    for (int k = 0; k < HC; k += 4) {
        float4 wr[4];
#pragma unroll
        for (int dk = 0; dk < 4; ++dk) wr[dk] = ((const float4*)W)[(k + dk) * 32 + jg];
#pragma unroll
        for (int r = 0; r < 8; ++r) {
            float4 xv = *(const float4*)&xs[ng * 8 + r][k];
            acc[r].x = fmaf(xv.x, wr[0].x, acc[r].x);
            acc[r].y = fmaf(xv.x, wr[0].y, acc[r].y);
            acc[r].z = fmaf(xv.x, wr[0].z, acc[r].z);
            acc[r].w = fmaf(xv.x, wr[0].w, acc[r].w);
            acc[r].x = fmaf(xv.y, wr[1].x, acc[r].x);
            acc[r].y = fmaf(xv.y, wr[1].y, acc[r].y);
            acc[r].z = fmaf(xv.y, wr[1].z, acc[r].z);
            acc[r].w = fmaf(xv.y, wr[1].w, acc[r].w);
            acc[r].x = fmaf(xv.z, wr[2].x, acc[r].x);
            acc[r].y = fmaf(xv.z, wr[2].y, acc[r].y);
            acc[r].z = fmaf(xv.z, wr[2].z, acc[r].z);
            acc[r].w = fmaf(xv.z, wr[2].w, acc[r].w);
            acc[r].x = fmaf(xv.w, wr[3].x, acc[r].x);
            acc[r].y = fmaf(xv.w, wr[3].y, acc[r].y);
            acc[r].z = fmaf(xv.w, wr[3].z, acc[r].z);
            acc[r].w = fmaf(xv.w, wr[3].w, acc[r].w);
        }
    }
    float4 asv = ((const float4*)a_src)[jg];
    float4 adv = ((const float4*)a_dst)[jg];
#pragma unroll
    for (int r = 0; r < 8; ++r) {
        int n = n0 + ng * 8 + r;
        float ps = acc[r].x * asv.x + acc[r].y * asv.y + acc[r].z * asv.z + acc[r].w * asv.w;
        float pd = acc[r].x * adv.x + acc[r].y * adv.y + acc[r].z * adv.z + acc[r].w * adv.w;
        ps += __shfl_xor(ps, 1); pd += __shfl_xor(pd, 1);
        ps += __shfl_xor(ps, 2); pd += __shfl_xor(pd, 2);
        ps += __shfl_xor(ps, 4); pd += __shfl_xor(pd, 4);
        if (n < NN) {
            ((uint2*)xwb)[(size_t)n * 32 + jg] =
                make_uint2(packbf2(acc[r].x, acc[r].y), packbf2(acc[r].z, acc[r].w));
            if ((jg & 7) == 0) {
                int h = jg >> 3;
                as_[n * HH + h] = ps;
                ad_[n * HH + h] = pd;
            }
        }
    }
}

// ---------------- fused segment softmax + aggregate + bias + ELU ----------------
// one wave per dst node; single pass (no max: |logit| < ~5 so exp is safe);
// bf16 gather table; 4 edges per wave-iteration (16 lanes x 16B each)
#define SWSTR 66
__global__ __launch_bounds__(256) void aggregate(
    const int* __restrict__ esrc, const int* __restrict__ row_start,
    const float* __restrict__ as_, const float* __restrict__ ad_,
    const unsigned* __restrict__ xwb, const float* __restrict__ bias,
    float* __restrict__ out) {
    __shared__ float2 sw_all[4][4 * SWSTR];
    int wid = (int)(threadIdx.x >> 6);
    int node = blockIdx.x * 4 + wid;
    if (node >= NN) return;
    int lane = threadIdx.x & 63;
    float2* sw = &sw_all[wid][0];
    int beg = row_start[node];
    int end = row_start[node + 1];
    float4 ad = ((const float4*)ad_)[node];

    int sub = lane >> 4;    // edge slot 0..3
    int c8 = lane & 15;     // cols c8*8 .. c8*8+7
    int h = c8 >> 2;        // head of those cols
    float4 accA = make_float4(0.f, 0.f, 0.f, 0.f);
    float4 accB = make_float4(0.f, 0.f, 0.f, 0.f);
    float d0 = 0.f, d1 = 0.f, d2 = 0.f, d3 = 0.f;

    for (int base = beg; base < end; base += 64) {
        int i = base + lane;
        int cnt = end - base; if (cnt > 64) cnt = 64;
        if (i < end) {
            int s = esrc[i];
            float4 av = ((const float4*)as_)[s];
            float w0 = __expf(lrelu(av.x + ad.x));
            float w1 = __expf(lrelu(av.y + ad.y));
            float w2 = __expf(lrelu(av.z + ad.z));
            float w3 = __expf(lrelu(av.w + ad.w));
            d0 += w0; d1 += w1; d2 += w2; d3 += w3;
            float sf = __int_as_float(s);
            sw[0 * SWSTR + lane] = make_float2(sf, w0);
            sw[1 * SWSTR + lane] = make_float2(sf, w1);
            sw[2 * SWSTR + lane] = make_float2(sf, w2);
            sw[3 * SWSTR + lane] = make_float2(sf, w3);
        }
        int iters = (cnt + 3) >> 2;
#pragma unroll 2
        for (int it = 0; it < iters; ++it) {
            int j = (it << 2) + sub;
            float2 swv = sw[h * SWSTR + j];
            bool ok = j < cnt;
            float wj = ok ? swv.y : 0.f;
            int sj = ok ? __float_as_int(swv.x) : 0;
            uint4 v = ((const uint4*)xwb)[(size_t)sj * 16 + c8];
            accA.x = fmaf(wj, __uint_as_float(v.x << 16), accA.x);
            accA.y = fmaf(wj, __uint_as_float(v.x & 0xffff0000u), accA.y);
            accA.z = fmaf(wj, __uint_as_float(v.y << 16), accA.z);
            accA.w = fmaf(wj, __uint_as_float(v.y & 0xffff0000u), accA.w);
            accB.x = fmaf(wj, __uint_as_float(v.z << 16), accB.x);
            accB.y = fmaf(wj, __uint_as_float(v.z & 0xffff0000u), accB.y);
            accB.z = fmaf(wj, __uint_as_float(v.w << 16), accB.z);
            accB.w = fmaf(wj, __uint_as_float(v.w & 0xffff0000u), accB.w);
        }
    }
    // sum the 4 edge-slot accumulators (lanes l, l^16, l^32, l^48 share cols)
#pragma unroll
    for (int off = 16; off <= 32; off <<= 1) {
        accA.x += __shfl_xor(accA.x, off);
        accA.y += __shfl_xor(accA.y, off);
        accA.z += __shfl_xor(accA.z, off);
        accA.w += __shfl_xor(accA.w, off);
        accB.x += __shfl_xor(accB.x, off);
        accB.y += __shfl_xor(accB.y, off);
        accB.z += __shfl_xor(accB.z, off);
        accB.w += __shfl_xor(accB.w, off);
    }
#pragma unroll
    for (int off = 32; off; off >>= 1) {
        d0 += __shfl_xor(d0, off);
        d1 += __shfl_xor(d1, off);
        d2 += __shfl_xor(d2, off);
        d3 += __shfl_xor(d3, off);
    }
    if (sub == 0) {
        float dn = h == 0 ? d0 : (h == 1 ? d1 : (h == 2 ? d2 : d3));
        float inv = 1.f / dn;
        float4 bb0 = ((const float4*)bias)[c8 * 2];
        float4 bb1 = ((const float4*)bias)[c8 * 2 + 1];
        float4 oA, oB;
        oA.x = fmaf(accA.x, inv, bb0.x);
        oA.y = fmaf(accA.y, inv, bb0.y);
        oA.z = fmaf(accA.z, inv, bb0.z);
        oA.w = fmaf(accA.w, inv, bb0.w);
        oB.x = fmaf(accB.x, inv, bb1.x);
        oB.y = fmaf(accB.y, inv, bb1.y);
        oB.z = fmaf(accB.z, inv, bb1.z);
        oB.w = fmaf(accB.w, inv, bb1.w);
        oA.x = oA.x > 0.f ? oA.x : expm1f(oA.x);
        oA.y = oA.y > 0.f ? oA.y : expm1f(oA.y);
        oA.z = oA.z > 0.f ? oA.z : expm1f(oA.z);
        oA.w = oA.w > 0.f ? oA.w : expm1f(oA.w);
        oB.x = oB.x > 0.f ? oB.x : expm1f(oB.x);
        oB.y = oB.y > 0.f ? oB.y : expm1f(oB.y);
        oB.z = oB.z > 0.f ? oB.z : expm1f(oB.z);
        oB.w = oB.w > 0.f ? oB.w : expm1f(oB.w);
        ((float4*)out)[(size_t)node * 32 + c8 * 2] = oA;
        ((float4*)out)[(size_t)node * 32 + c8 * 2 + 1] = oB;
    }
}

// ---------------- pooling + head ----------------
__global__ __launch_bounds__(128) void pool(
    const float* __restrict__ h1, const int* __restrict__ batch,
    float* __restrict__ sums, float* __restrict__ cnts) {
    int j = threadIdx.x;
    int n0 = blockIdx.x * 64;
    int n1 = n0 + 64; if (n1 > NN) n1 = NN;
    if (n0 >= NN) return;
    int cur = batch[n0];
    float local = 0.f;
    int cnt = 0;
    for (int n = n0; n < n1; ++n) {
        int g = batch[n];
        if (g != cur) {
            atomicAdd(&sums[cur * HC + j], local);
            if (j == 0) atomicAdd(&cnts[cur], (float)cnt);
            local = 0.f; cnt = 0; cur = g;
        }
        local += h1[(size_t)n * HC + j];
        ++cnt;
    }
    atomicAdd(&sums[cur * HC + j], local);
    if (j == 0) atomicAdd(&cnts[cur], (float)cnt);
}

__global__ __launch_bounds__(128) void head_out(
    const float* __restrict__ sums, const float* __restrict__ cnts,
    const float* __restrict__ lin_w, const float* __restrict__ lin_b,
    float* __restrict__ out) {
    int g = blockIdx.x;
    int j = threadIdx.x;
    float c = cnts[g];
    c = c > 1.f ? c : 1.f;
    float v = sums[g * HC + j] / c * lin_w[j];
    __shared__ float red[HC];
    red[j] = v;
    __syncthreads();
    for (int off = 64; off > 0; off >>= 1) {
        if (j < off) red[j] += red[j + off];
        __syncthreads();
    }
    if (j == 0) out[g] = red[0] + lin_b[0];
}

extern "C" void kernel_launch(void* const* d_in, const int* in_sizes, int n_in,
                              void* d_out, int out_size, void* d_ws, size_t ws_size,
                              hipStream_t stream) {
    const float* x   = (const float*)d_in[0];
    const int*   ei  = (const int*)d_in[1];
    const int*   bat = (const int*)d_in[2];
    const float* W0  = (const float*)d_in[3];
    const float* as0 = (const float*)d_in[4];
    const float* ad0 = (const float*)d_in[5];
    const float* b0  = (const float*)d_in[6];
    const float* W1  = (const float*)d_in[7];
    const float* as1 = (const float*)d_in[8];
    const float* ad1 = (const float*)d_in[9];
    const float* b1  = (const float*)d_in[10];
    const float* lw  = (const float*)d_in[11];
    const float* lb  = (const float*)d_in[12];
    float* out = (float*)d_out;

    char* w = (char*)d_ws;
    unsigned* xwb = (unsigned*)w; w += (size_t)NN * HC * 2;   // 12.8 MB bf16
    float* h0  = (float*)w;  w += (size_t)NN * HC * 4;        // 25.6 MB
    float* as_ = (float*)w;  w += (size_t)NN * HH * 4;
    float* ad_ = (float*)w;  w += (size_t)NN * HH * 4;
    int* deg       = (int*)w; w += (size_t)NN * 4;
    int* row_start = (int*)w; w += (size_t)(NN + 1) * 4;
    int* cursor    = (int*)w; w += (size_t)NN * 4;
    int* esrc      = (int*)w; w += (size_t)NEDGE * 4;
    float* sums = (float*)w; w += (size_t)GG * HC * 4;
    float* cnts = (float*)w; w += (size_t)GG * 4;

    const int gb = (NN + GMT - 1) / GMT;
    const int ab = (NN + 3) / 4;

    // ---- CSR build (shared by both layers) ----
    hipMemsetAsync(deg, 0, (size_t)NN * 4, stream);
    hist<<<(EE + 255) / 256, 256, 0, stream>>>(ei, deg);
    scan_deg<<<1, 1024, 0, stream>>>(deg, row_start, cursor);
    scatter2<<<NXCD * SB, 256, 0, stream>>>(ei, cursor, esrc);

    // ---- layer 0 ----
    gemm_alpha<<<gb, 256, 0, stream>>>(x, W0, as0, ad0, xwb, as_, ad_);
    aggregate<<<ab, 256, 0, stream>>>(esrc, row_start, as_, ad_, xwb, b0, h0);

    // ---- layer 1 ----
    gemm_alpha<<<gb, 256, 0, stream>>>(h0, W1, as1, ad1, xwb, as_, ad_);
    aggregate<<<ab, 256, 0, stream>>>(esrc, row_start, as_, ad_, xwb, b1, h0);

    // ---- pool + head ----
    hipMemsetAsync(sums, 0, ((size_t)GG * HC + GG) * 4, stream);
    pool<<<(NN + 63) / 64, 128, 0, stream>>>(h0, bat, sums, cnts);
    head_out<<<GG, 128, 0, stream>>>(sums, cnts, lw, lb, out);
}

// Round 8
// 373.547 us; speedup vs baseline: 2.1956x; 1.2682x over previous
//
#include <hip/hip_runtime.h>
#include <hip/hip_bf16.h>

#define NN 50000
#define EE 1600000
#define NEDGE (EE + NN)   // with self loops
#define HH 4
#define HC 128
#define GG 64
#define GMT 64            // nodes per gemm block
#define NXCD 8
#define RNG (NN / NXCD)   // 6250 nodes per XCD group
#define SB 256            // scatter sub-blocks per group (2048 blocks total)
#define NSB ((NN + 255) / 256)   // 196 scan blocks

__device__ __forceinline__ float lrelu(float x) { return x > 0.f ? x : 0.2f * x; }

// round-to-nearest-even f32 -> bf16 (as u16), pack two into a uint
__device__ __forceinline__ unsigned packbf2(float a, float b) {
    unsigned ua = __float_as_uint(a);
    ua = (ua + 0x7fffu + ((ua >> 16) & 1u)) >> 16;
    unsigned ub = __float_as_uint(b);
    ub = (ub + 0x7fffu + ((ub >> 16) & 1u)) >> 16;
    return ua | (ub << 16);
}

// ---------------- CSR build ----------------
__global__ __launch_bounds__(256) void hist(const int* __restrict__ ei, int* __restrict__ deg) {
    int i = blockIdx.x * 256 + threadIdx.x;
    if (i >= EE) return;
    atomicAdd(&deg[ei[EE + i]], 1);
}

// two-level scan of (deg[i]+1): per-block pass
__global__ __launch_bounds__(256) void scan1(const int* __restrict__ deg,
                                             int* __restrict__ row_start,
                                             int* __restrict__ bsum) {
    int b = blockIdx.x, t = threadIdx.x;
    int i = b * 256 + t;
    int v = (i < NN) ? deg[i] + 1 : 0;
    int lane = t & 63, wv = t >> 6;
    int x = v;
#pragma unroll
    for (int off = 1; off < 64; off <<= 1) {
        int y = __shfl_up(x, off);
        if (lane >= off) x += y;
    }
    __shared__ int wsum[4], woff[4];
    if (lane == 63) wsum[wv] = x;
    __syncthreads();
    if (t == 0) {
        int r = 0;
#pragma unroll
        for (int k = 0; k < 4; ++k) { woff[k] = r; r += wsum[k]; }
        bsum[b] = r;
    }
    __syncthreads();
    if (i < NN) row_start[i] = x - v + woff[wv];   // within-block exclusive
}

// exclusive scan of the NSB block sums (single small block)
__global__ __launch_bounds__(256) void scan2(int* __restrict__ bsum) {
    int t = threadIdx.x;
    int v = (t < NSB) ? bsum[t] : 0;
    int lane = t & 63, wv = t >> 6;
    int x = v;
#pragma unroll
    for (int off = 1; off < 64; off <<= 1) {
        int y = __shfl_up(x, off);
        if (lane >= off) x += y;
    }
    __shared__ int wsum[4], woff[4];
    if (lane == 63) wsum[wv] = x;
    __syncthreads();
    if (t == 0) {
        int r = 0;
#pragma unroll
        for (int k = 0; k < 4; ++k) { woff[k] = r; r += wsum[k]; }
    }
    __syncthreads();
    if (t < NSB) bsum[t] = x - v + woff[wv];       // exclusive block offset
}

// add block offsets; write row_start AND cursor; set sentinel
__global__ __launch_bounds__(256) void scan3(int* __restrict__ row_start,
                                             const int* __restrict__ bsum,
                                             int* __restrict__ cursor) {
    int i = blockIdx.x * 256 + threadIdx.x;
    if (i < NN) {
        int v = row_start[i] + bsum[i >> 8];
        row_start[i] = v;
        cursor[i] = v;
    } else if (i == NN) {
        row_start[NN] = NEDGE;
    }
}

// XCD-range-partitioned scatter (write locality), full-occupancy grid
__global__ __launch_bounds__(256) void scatter2(const int* __restrict__ ei, int* __restrict__ cursor,
                                                int* __restrict__ esrc) {
    int g = blockIdx.x & (NXCD - 1);
    int sub = blockIdx.x >> 3;
    int t = threadIdx.x;
    int lo = g * RNG;
    const int per = (EE + SB - 1) / SB;
    int e0 = sub * per, e1 = e0 + per; if (e1 > EE) e1 = EE;
    for (int i = e0 + t; i < e1; i += 256) {
        int d = ei[EE + i];
        unsigned r = (unsigned)(d - lo);
        if (r < RNG) {
            int s = ei[i];
            int pos = atomicAdd(&cursor[d], 1);
            esrc[pos] = s;
        }
    }
    const int perN = (RNG + SB - 1) / SB;
    int n0 = lo + sub * perN, n1 = n0 + perN; if (n1 > lo + RNG) n1 = lo + RNG;
    for (int n = n0 + t; n < n1; n += 256) {
        int pos = atomicAdd(&cursor[n], 1);
        esrc[pos] = n;
    }
}

// ---------------- GEMM (X @ W) + per-head alpha dots; bf16-packed output ----------------
__global__ __launch_bounds__(256) void gemm_alpha(
    const float* __restrict__ X, const float* __restrict__ W,
    const float* __restrict__ a_src, const float* __restrict__ a_dst,
    unsigned* __restrict__ xwb, float* __restrict__ as_, float* __restrict__ ad_) {
    __shared__ float xs[GMT][HC + 4];
    int tid = threadIdx.x;
    int n0 = blockIdx.x * GMT;
    for (int i = tid; i < GMT * (HC / 4); i += 256) {
        int r = i >> 5, c4 = i & 31;
        int n = n0 + r;
        float4 v = (n < NN) ? ((const float4*)X)[(size_t)n * 32 + c4]
                            : make_float4(0.f, 0.f, 0.f, 0.f);
        *(float4*)&xs[r][c4 * 4] = v;
    }
    __syncthreads();

    int jg = tid & 31;
    int ng = tid >> 5;
    float4 acc[8] = {};
    for (int k = 0; k < HC; k += 4) {
        float4 wr[4];
#pragma unroll
        for (int dk = 0; dk < 4; ++dk) wr[dk] = ((const float4*)W)[(k + dk) * 32 + jg];
#pragma unroll
        for (int r = 0; r < 8; ++r) {
            float4 xv = *(const float4*)&xs[ng * 8 + r][k];
            acc[r].x = fmaf(xv.x, wr[0].x, acc[r].x);
            acc[r].y = fmaf(xv.x, wr[0].y, acc[r].y);
            acc[r].z = fmaf(xv.x, wr[0].z, acc[r].z);
            acc[r].w = fmaf(xv.x, wr[0].w, acc[r].w);
            acc[r].x = fmaf(xv.y, wr[1].x, acc[r].x);
            acc[r].y = fmaf(xv.y, wr[1].y, acc[r].y);
            acc[r].z = fmaf(xv.y, wr[1].z, acc[r].z);
            acc[r].w = fmaf(xv.y, wr[1].w, acc[r].w);
            acc[r].x = fmaf(xv.z, wr[2].x, acc[r].x);
            acc[r].y = fmaf(xv.z, wr[2].y, acc[r].y);
            acc[r].z = fmaf(xv.z, wr[2].z, acc[r].z);
            acc[r].w = fmaf(xv.z, wr[2].w, acc[r].w);
            acc[r].x = fmaf(xv.w, wr[3].x, acc[r].x);
            acc[r].y = fmaf(xv.w, wr[3].y, acc[r].y);
            acc[r].z = fmaf(xv.w, wr[3].z, acc[r].z);
            acc[r].w = fmaf(xv.w, wr[3].w, acc[r].w);
        }
    }
    float4 asv = ((const float4*)a_src)[jg];
    float4 adv = ((const float4*)a_dst)[jg];
#pragma unroll
    for (int r = 0; r < 8; ++r) {
        int n = n0 + ng * 8 + r;
        float ps = acc[r].x * asv.x + acc[r].y * asv.y + acc[r].z * asv.z + acc[r].w * asv.w;
        float pd = acc[r].x * adv.x + acc[r].y * adv.y + acc[r].z * adv.z + acc[r].w * adv.w;
        ps += __shfl_xor(ps, 1); pd += __shfl_xor(pd, 1);
        ps += __shfl_xor(ps, 2); pd += __shfl_xor(pd, 2);
        ps += __shfl_xor(ps, 4); pd += __shfl_xor(pd, 4);
        if (n < NN) {
            ((uint2*)xwb)[(size_t)n * 32 + jg] =
                make_uint2(packbf2(acc[r].x, acc[r].y), packbf2(acc[r].z, acc[r].w));
            if ((jg & 7) == 0) {
                int h = jg >> 3;
                as_[n * HH + h] = ps;
                ad_[n * HH + h] = pd;
            }
        }
    }
}

// ---------------- fused segment softmax + aggregate + bias + ELU ----------------
#define SWSTR 66
__global__ __launch_bounds__(256) void aggregate(
    const int* __restrict__ esrc, const int* __restrict__ row_start,
    const float* __restrict__ as_, const float* __restrict__ ad_,
    const unsigned* __restrict__ xwb, const float* __restrict__ bias,
    float* __restrict__ out) {
    __shared__ float2 sw_all[4][4 * SWSTR];
    int wid = (int)(threadIdx.x >> 6);
    int node = blockIdx.x * 4 + wid;
    if (node >= NN) return;
    int lane = threadIdx.x & 63;
    float2* sw = &sw_all[wid][0];
    int beg = row_start[node];
    int end = row_start[node + 1];
    float4 ad = ((const float4*)ad_)[node];

    int sub = lane >> 4;    // edge slot 0..3
    int c8 = lane & 15;     // cols c8*8 .. c8*8+7
    int h = c8 >> 2;        // head of those cols
    float4 accA = make_float4(0.f, 0.f, 0.f, 0.f);
    float4 accB = make_float4(0.f, 0.f, 0.f, 0.f);
    float d0 = 0.f, d1 = 0.f, d2 = 0.f, d3 = 0.f;

    for (int base = beg; base < end; base += 64) {
        int i = base + lane;
        int cnt = end - base; if (cnt > 64) cnt = 64;
        if (i < end) {
            int s = esrc[i];
            float4 av = ((const float4*)as_)[s];
            float w0 = __expf(lrelu(av.x + ad.x));
            float w1 = __expf(lrelu(av.y + ad.y));
            float w2 = __expf(lrelu(av.z + ad.z));
            float w3 = __expf(lrelu(av.w + ad.w));
            d0 += w0; d1 += w1; d2 += w2; d3 += w3;
            float sf = __int_as_float(s);
            sw[0 * SWSTR + lane] = make_float2(sf, w0);
            sw[1 * SWSTR + lane] = make_float2(sf, w1);
            sw[2 * SWSTR + lane] = make_float2(sf, w2);
            sw[3 * SWSTR + lane] = make_float2(sf, w3);
        }
        int iters = (cnt + 3) >> 2;
#pragma unroll 2
        for (int it = 0; it < iters; ++it) {
            int j = (it << 2) + sub;
            float2 swv = sw[h * SWSTR + j];
            bool ok = j < cnt;
            float wj = ok ? swv.y : 0.f;
            int sj = ok ? __float_as_int(swv.x) : 0;
            uint4 v = ((const uint4*)xwb)[(size_t)sj * 16 + c8];
            accA.x = fmaf(wj, __uint_as_float(v.x << 16), accA.x);
            accA.y = fmaf(wj, __uint_as_float(v.x & 0xffff0000u), accA.y);
            accA.z = fmaf(wj, __uint_as_float(v.y << 16), accA.z);
            accA.w = fmaf(wj, __uint_as_float(v.y & 0xffff0000u), accA.w);
            accB.x = fmaf(wj, __uint_as_float(v.z << 16), accB.x);
            accB.y = fmaf(wj, __uint_as_float(v.z & 0xffff0000u), accB.y);
            accB.z = fmaf(wj, __uint_as_float(v.w << 16), accB.z);
            accB.w = fmaf(wj, __uint_as_float(v.w & 0xffff0000u), accB.w);
        }
    }
#pragma unroll
    for (int off = 16; off <= 32; off <<= 1) {
        accA.x += __shfl_xor(accA.x, off);
        accA.y += __shfl_xor(accA.y, off);
        accA.z += __shfl_xor(accA.z, off);
        accA.w += __shfl_xor(accA.w, off);
        accB.x += __shfl_xor(accB.x, off);
        accB.y += __shfl_xor(accB.y, off);
        accB.z += __shfl_xor(accB.z, off);
        accB.w += __shfl_xor(accB.w, off);
    }
#pragma unroll
    for (int off = 32; off; off >>= 1) {
        d0 += __shfl_xor(d0, off);
        d1 += __shfl_xor(d1, off);
        d2 += __shfl_xor(d2, off);
        d3 += __shfl_xor(d3, off);
    }
    if (sub == 0) {
        float dn = h == 0 ? d0 : (h == 1 ? d1 : (h == 2 ? d2 : d3));
        float inv = 1.f / dn;
        float4 bb0 = ((const float4*)bias)[c8 * 2];
        float4 bb1 = ((const float4*)bias)[c8 * 2 + 1];
        float4 oA, oB;
        oA.x = fmaf(accA.x, inv, bb0.x);
        oA.y = fmaf(accA.y, inv, bb0.y);
        oA.z = fmaf(accA.z, inv, bb0.z);
        oA.w = fmaf(accA.w, inv, bb0.w);
        oB.x = fmaf(accB.x, inv, bb1.x);
        oB.y = fmaf(accB.y, inv, bb1.y);
        oB.z = fmaf(accB.z, inv, bb1.z);
        oB.w = fmaf(accB.w, inv, bb1.w);
        oA.x = oA.x > 0.f ? oA.x : expm1f(oA.x);
        oA.y = oA.y > 0.f ? oA.y : expm1f(oA.y);
        oA.z = oA.z > 0.f ? oA.z : expm1f(oA.z);
        oA.w = oA.w > 0.f ? oA.w : expm1f(oA.w);
        oB.x = oB.x > 0.f ? oB.x : expm1f(oB.x);
        oB.y = oB.y > 0.f ? oB.y : expm1f(oB.y);
        oB.z = oB.z > 0.f ? oB.z : expm1f(oB.z);
        oB.w = oB.w > 0.f ? oB.w : expm1f(oB.w);
        ((float4*)out)[(size_t)node * 32 + c8 * 2] = oA;
        ((float4*)out)[(size_t)node * 32 + c8 * 2 + 1] = oB;
    }
}

// ---------------- pooling + head ----------------
__global__ __launch_bounds__(128) void pool(
    const float* __restrict__ h1, const int* __restrict__ batch,
    float* __restrict__ sums, float* __restrict__ cnts) {
    int j = threadIdx.x;
    int n0 = blockIdx.x * 64;
    int n1 = n0 + 64; if (n1 > NN) n1 = NN;
    if (n0 >= NN) return;
    int cur = batch[n0];
    float local = 0.f;
    int cnt = 0;
    for (int n = n0; n < n1; ++n) {
        int g = batch[n];
        if (g != cur) {
            atomicAdd(&sums[cur * HC + j], local);
            if (j == 0) atomicAdd(&cnts[cur], (float)cnt);
            local = 0.f; cnt = 0; cur = g;
        }
        local += h1[(size_t)n * HC + j];
        ++cnt;
    }
    atomicAdd(&sums[cur * HC + j], local);
    if (j == 0) atomicAdd(&cnts[cur], (float)cnt);
}

__global__ __launch_bounds__(128) void head_out(
    const float* __restrict__ sums, const float* __restrict__ cnts,
    const float* __restrict__ lin_w, const float* __restrict__ lin_b,
    float* __restrict__ out) {
    int g = blockIdx.x;
    int j = threadIdx.x;
    float c = cnts[g];
    c = c > 1.f ? c : 1.f;
    float v = sums[g * HC + j] / c * lin_w[j];
    __shared__ float red[HC];
    red[j] = v;
    __syncthreads();
    for (int off = 64; off > 0; off >>= 1) {
        if (j < off) red[j] += red[j + off];
        __syncthreads();
    }
    if (j == 0) out[g] = red[0] + lin_b[0];
}

extern "C" void kernel_launch(void* const* d_in, const int* in_sizes, int n_in,
                              void* d_out, int out_size, void* d_ws, size_t ws_size,
                              hipStream_t stream) {
    const float* x   = (const float*)d_in[0];
    const int*   ei  = (const int*)d_in[1];
    const int*   bat = (const int*)d_in[2];
    const float* W0  = (const float*)d_in[3];
    const float* as0 = (const float*)d_in[4];
    const float* ad0 = (const float*)d_in[5];
    const float* b0  = (const float*)d_in[6];
    const float* W1  = (const float*)d_in[7];
    const float* as1 = (const float*)d_in[8];
    const float* ad1 = (const float*)d_in[9];
    const float* b1  = (const float*)d_in[10];
    const float* lw  = (const float*)d_in[11];
    const float* lb  = (const float*)d_in[12];
    float* out = (float*)d_out;

    char* w = (char*)d_ws;
    unsigned* xwb = (unsigned*)w; w += (size_t)NN * HC * 2;   // 12.8 MB bf16
    float* h0  = (float*)w;  w += (size_t)NN * HC * 4;        // 25.6 MB
    float* as_ = (float*)w;  w += (size_t)NN * HH * 4;
    float* ad_ = (float*)w;  w += (size_t)NN * HH * 4;
    int* deg       = (int*)w; w += (size_t)NN * 4;
    int* row_start = (int*)w; w += (size_t)(NN + 1) * 4;
    int* cursor    = (int*)w; w += (size_t)NN * 4;
    int* bsum      = (int*)w; w += (size_t)NSB * 4;
    int* esrc      = (int*)w; w += (size_t)NEDGE * 4;
    float* sums = (float*)w; w += (size_t)GG * HC * 4;
    float* cnts = (float*)w; w += (size_t)GG * 4;

    const int gb = (NN + GMT - 1) / GMT;
    const int ab = (NN + 3) / 4;

    // ---- CSR build (shared by both layers) ----
    hipMemsetAsync(deg, 0, (size_t)NN * 4, stream);
    hist<<<(EE + 255) / 256, 256, 0, stream>>>(ei, deg);
    scan1<<<NSB, 256, 0, stream>>>(deg, row_start, bsum);
    scan2<<<1, 256, 0, stream>>>(bsum);
    scan3<<<(NN + 256) / 256, 256, 0, stream>>>(row_start, bsum, cursor);
    scatter2<<<NXCD * SB, 256, 0, stream>>>(ei, cursor, esrc);

    // ---- layer 0 ----
    gemm_alpha<<<gb, 256, 0, stream>>>(x, W0, as0, ad0, xwb, as_, ad_);
    aggregate<<<ab, 256, 0, stream>>>(esrc, row_start, as_, ad_, xwb, b0, h0);

    // ---- layer 1 ----
    gemm_alpha<<<gb, 256, 0, stream>>>(h0, W1, as1, ad1, xwb, as_, ad_);
    aggregate<<<ab, 256, 0, stream>>>(esrc, row_start, as_, ad_, xwb, b1, h0);

    // ---- pool + head ----
    hipMemsetAsync(sums, 0, ((size_t)GG * HC + GG) * 4, stream);
    pool<<<(NN + 63) / 64, 128, 0, stream>>>(h0, bat, sums, cnts);
    head_out<<<GG, 128, 0, stream>>>(sums, cnts, lw, lb, out);
}